// Round 1
// baseline (1147.179 us; speedup 1.0000x reference)
//
#include <hip/hip_runtime.h>
#include <hip/hip_bf16.h>
#include <stdint.h>

typedef __bf16 bf16x8 __attribute__((ext_vector_type(8)));
typedef float f32x4 __attribute__((ext_vector_type(4)));
typedef float f32x4v __attribute__((ext_vector_type(4)));
typedef unsigned short u16x4 __attribute__((ext_vector_type(4)));

__device__ __forceinline__ unsigned short f2bf(float f) {
    union { float f; uint32_t u; } v; v.f = f;
    uint32_t u = v.u;
    return (unsigned short)((u + 0x7fffu + ((u >> 16) & 1u)) >> 16);
}

// ---- prep: f32 -> bf16 feature conversion (vectorized x4) ----
__global__ __launch_bounds__(256) void prep_x(const f32x4* __restrict__ x,
                                              u16x4* __restrict__ xb, int n4) {
    int t = blockIdx.x * 256 + threadIdx.x;
    if (t < n4) {
        f32x4 v = x[t];
        u16x4 o;
        o.x = f2bf(v.x); o.y = f2bf(v.y); o.z = f2bf(v.z); o.w = f2bf(v.w);
        xb[t] = o;
    }
}

// ---- prep: W[k][ci][co] f32 -> Wt[k][co][ci] bf16 (one block per k) ----
__global__ __launch_bounds__(256) void prep_w(const float* __restrict__ W,
                                              unsigned short* __restrict__ Wt) {
    int k = blockIdx.x;
    const float* Wk = W + (size_t)k * 4096;
    unsigned short* Wtk = Wt + (size_t)k * 4096;
    for (int j = threadIdx.x; j < 4096; j += 256) {
        int ci = j >> 6, co = j & 63;
        Wtk[co * 64 + ci] = f2bf(Wk[j]);
    }
}

// ---- detect mask element width: 0=int32, 1=bytes(bool), 2=float32 ----
__global__ void detect_mask(const unsigned int* __restrict__ m, int* __restrict__ flag) {
    __shared__ int s_not_int, s_not_f32;
    if (threadIdx.x == 0) { s_not_int = 0; s_not_f32 = 0; }
    __syncthreads();
    unsigned int w = m[threadIdx.x];          // first 4KB: safe for all widths
    if (w > 1u) s_not_int = 1;                // benign race
    if (w != 0u && w != 0x3f800000u) s_not_f32 = 1;
    __syncthreads();
    if (threadIdx.x == 0) *flag = s_not_int ? (s_not_f32 ? 1 : 2) : 0;
}

// ---- main sparse conv: gather -> MFMA -> accumulate ----
// MODE 0: out = bf16 relu(acc + bias)   (hidden layer)
// MODE 1: out = f32  acc + bias + resid (final layer)
template <int MODE>
__global__ __launch_bounds__(256) void conv_mfma(
    const unsigned short* __restrict__ xb,   // [N][64] bf16
    const int* __restrict__ nbr,             // [N][K]
    const void* __restrict__ maskp,
    const int* __restrict__ flagp,
    const unsigned short* __restrict__ Wt,   // [K][64(co)][64(ci)] bf16
    const float* __restrict__ bias,          // [64]
    const float* __restrict__ resid,         // [N][64] f32 (MODE 1)
    void* __restrict__ outp,
    int N, int K)
{
    const int tid = threadIdx.x;
    const int w = tid >> 6;        // wave 0..3
    const int l = tid & 63;
    const int lr = l & 15;         // fragment row/col index
    const int lh = l >> 4;         // 0..3 k-slice group
    const int base = blockIdx.x * 64;
    const int i = base + w * 16 + lr;   // this lane's gathered A-row
    const bool vi = i < N;

    // preload this row's 27 mask bits (uniform branch on detected dtype)
    unsigned int mbits = 0;
    const int flag = *flagp;
    if (vi) {
        long off = (long)i * K;
        if (flag == 1) {
            const unsigned char* mp = (const unsigned char*)maskp + off;
            for (int k = 0; k < K; ++k) mbits |= (mp[k] ? 1u : 0u) << k;
        } else if (flag == 0) {
            const int* mp = (const int*)maskp + off;
            for (int k = 0; k < K; ++k) mbits |= (mp[k] ? 1u : 0u) << k;
        } else {
            const float* mp = (const float*)maskp + off;
            for (int k = 0; k < K; ++k) mbits |= ((mp[k] != 0.f) ? 1u : 0u) << k;
        }
    }

    const int* nrow = nbr + (long)i * K;
    f32x4 acc[4] = {};

    for (int k = 0; k < K; ++k) {
        bf16x8 a0 = {}, a1 = {};
        if (vi && ((mbits >> k) & 1u)) {
            int g = nrow[k];
            const unsigned short* src = xb + ((long)g << 6) + (lh << 3);
            a0 = *(const bf16x8*)src;          // ci 8*lh .. 8*lh+7
            a1 = *(const bf16x8*)(src + 32);   // ci 32 + 8*lh ..
        }
        const unsigned short* wk = Wt + ((long)k << 12) + lr * 64 + (lh << 3);
#pragma unroll
        for (int cb = 0; cb < 4; ++cb) {
            bf16x8 b0 = *(const bf16x8*)(wk + cb * 1024);
            bf16x8 b1 = *(const bf16x8*)(wk + cb * 1024 + 32);
            acc[cb] = __builtin_amdgcn_mfma_f32_16x16x32_bf16(a0, b0, acc[cb], 0, 0, 0);
            acc[cb] = __builtin_amdgcn_mfma_f32_16x16x32_bf16(a1, b1, acc[cb], 0, 0, 0);
        }
    }

    // epilogue: D row = 4*lh + r (within wave tile), col = cb*16 + lr
#pragma unroll
    for (int cb = 0; cb < 4; ++cb) {
        int col = cb * 16 + lr;
        float bv = bias[col];
#pragma unroll
        for (int r = 0; r < 4; ++r) {
            int orow = base + w * 16 + lh * 4 + r;
            if (orow < N) {
                long o = (long)orow * 64 + col;
                float v = acc[cb][r] + bv;
                if (MODE == 0) {
                    v = fmaxf(v, 0.f);
                    ((unsigned short*)outp)[o] = f2bf(v);
                } else {
                    ((float*)outp)[o] = v + resid[o];
                }
            }
        }
    }
}

static inline size_t align256(size_t x) { return (x + 255) & ~(size_t)255; }

extern "C" void kernel_launch(void* const* d_in, const int* in_sizes, int n_in,
                              void* d_out, int out_size, void* d_ws, size_t ws_size,
                              hipStream_t stream) {
    const float* x    = (const float*)d_in[0];
    const int*   nbr  = (const int*)d_in[1];
    const void*  mask = d_in[2];
    const float* W0   = (const float*)d_in[3];
    const float* b0   = (const float*)d_in[4];
    const float* W1   = (const float*)d_in[5];
    const float* b1   = (const float*)d_in[6];

    const int NC = in_sizes[0];      // N*64
    const int N  = NC / 64;
    const int K  = in_sizes[1] / N;  // 27

    char* ws = (char*)d_ws;
    size_t xb_bytes = (size_t)NC * 2;
    size_t wt_bytes = (size_t)K * 64 * 64 * 2;
    size_t xb_off   = 0;
    size_t hb_off   = xb_off + align256(xb_bytes);
    size_t wt0_off  = hb_off + align256(xb_bytes);
    size_t wt1_off  = wt0_off + align256(wt_bytes);
    size_t flag_off = wt1_off + align256(wt_bytes);

    unsigned short* xb  = (unsigned short*)(ws + xb_off);
    unsigned short* hb  = (unsigned short*)(ws + hb_off);
    unsigned short* wt0 = (unsigned short*)(ws + wt0_off);
    unsigned short* wt1 = (unsigned short*)(ws + wt1_off);
    int* flag           = (int*)(ws + flag_off);

    int n4 = NC / 4;
    prep_x<<<(n4 + 255) / 256, 256, 0, stream>>>((const f32x4*)x, (u16x4*)xb, n4);
    prep_w<<<K, 256, 0, stream>>>(W0, wt0);
    prep_w<<<K, 256, 0, stream>>>(W1, wt1);
    detect_mask<<<1, 1024, 0, stream>>>((const unsigned int*)mask, flag);

    int nblocks = (N + 63) / 64;
    conv_mfma<0><<<nblocks, 256, 0, stream>>>(xb, nbr, mask, flag, wt0, b0, nullptr, hb, N, K);
    conv_mfma<1><<<nblocks, 256, 0, stream>>>(hb, nbr, mask, flag, wt1, b1, x, d_out, N, K);
}

// Round 2
// 1100.714 us; speedup vs baseline: 1.0422x; 1.0422x over previous
//
#include <hip/hip_runtime.h>
#include <hip/hip_bf16.h>
#include <stdint.h>

typedef __bf16 bf16x8 __attribute__((ext_vector_type(8)));
typedef float f32x4 __attribute__((ext_vector_type(4)));
typedef unsigned short u16x4 __attribute__((ext_vector_type(4)));

__device__ __forceinline__ unsigned short f2bf(float f) {
    union { float f; uint32_t u; } v; v.f = f;
    uint32_t u = v.u;
    return (unsigned short)((u + 0x7fffu + ((u >> 16) & 1u)) >> 16);
}

// ---- prep: f32 -> bf16 feature conversion (vectorized x4) ----
__global__ __launch_bounds__(256) void prep_x(const f32x4* __restrict__ x,
                                              u16x4* __restrict__ xb, int n4) {
    int t = blockIdx.x * 256 + threadIdx.x;
    if (t < n4) {
        f32x4 v = x[t];
        u16x4 o;
        o.x = f2bf(v.x); o.y = f2bf(v.y); o.z = f2bf(v.z); o.w = f2bf(v.w);
        xb[t] = o;
    }
}

// ---- prep: W[k][ci][co] f32 -> Wt[k][co][ci] bf16; blocks k>=K write zeros ----
__global__ __launch_bounds__(256) void prep_w(const float* __restrict__ W,
                                              unsigned short* __restrict__ Wt, int K) {
    int k = blockIdx.x;
    unsigned short* Wtk = Wt + (size_t)k * 4096;
    if (k >= K) {
        for (int j = threadIdx.x; j < 4096; j += 256) Wtk[j] = 0;
        return;
    }
    const float* Wk = W + (size_t)k * 4096;
    for (int j = threadIdx.x; j < 4096; j += 256) {
        int ci = j >> 6, co = j & 63;
        Wtk[co * 64 + ci] = f2bf(Wk[j]);
    }
}

// ---- detect mask element width: 0=int32, 1=bytes(bool), 2=float32 ----
__global__ void detect_mask(const unsigned int* __restrict__ m, int* __restrict__ flag) {
    __shared__ int s_not_int, s_not_f32;
    if (threadIdx.x == 0) { s_not_int = 0; s_not_f32 = 0; }
    __syncthreads();
    unsigned int w = m[threadIdx.x];          // first 4KB: safe for all widths
    if (w > 1u) s_not_int = 1;                // benign race
    if (w != 0u && w != 0x3f800000u) s_not_f32 = 1;
    __syncthreads();
    if (threadIdx.x == 0) *flag = s_not_int ? (s_not_f32 ? 1 : 2) : 0;
}

// ---- main sparse conv: deep-prefetch gather -> MFMA -> accumulate ----
// Specialized for K <= 28 (K=27), unrolled in 4 groups of 7 with 14
// gather loads in flight per group for memory-level parallelism.
// MODE 0: out = bf16 relu(acc + bias)   (hidden layer)
// MODE 1: out = f32  acc + bias + resid (final layer)
template <int MODE>
__global__ void conv_mfma(
    const unsigned short* __restrict__ xb,   // [N][64] bf16
    const int* __restrict__ nbr,             // [N][K]
    const void* __restrict__ maskp,
    const int* __restrict__ flagp,
    const unsigned short* __restrict__ Wt,   // [28][64(co)][64(ci)] bf16
    const float* __restrict__ bias,          // [64]
    const float* __restrict__ resid,         // [N][64] f32 (MODE 1)
    void* __restrict__ outp,
    int N, int K)
{
    const int tid = threadIdx.x;
    const int w = tid >> 6;        // wave 0..3
    const int l = tid & 63;
    const int lr = l & 15;         // fragment row/col index
    const int lh = l >> 4;         // 0..3 k-slice group
    const int base = blockIdx.x * 64;
    int i = base + w * 16 + lr;    // this lane's gathered A-row
    if (i >= N) i = N - 1;         // clamp (epilogue re-guards); avoids OOB

    // ---- preload this row's mask bits (uniform branch on detected dtype) ----
    unsigned int mbits = 0;
    {
        const int flag = *flagp;
        long off = (long)i * K;
        if (flag == 1) {
            const unsigned char* mp = (const unsigned char*)maskp + off;
#pragma unroll
            for (int k = 0; k < 27; ++k) mbits |= (mp[k] ? 1u : 0u) << k;
        } else if (flag == 0) {
            const int* mp = (const int*)maskp + off;
#pragma unroll
            for (int k = 0; k < 27; ++k) mbits |= (mp[k] ? 1u : 0u) << k;
        } else {
            const float* mp = (const float*)maskp + off;
#pragma unroll
            for (int k = 0; k < 27; ++k) mbits |= ((mp[k] != 0.f) ? 1u : 0u) << k;
        }
    }

    // ---- preload all neighbor indices into registers ----
    int g[28];
    {
        const int* nrow = nbr + (long)i * K;
#pragma unroll
        for (int k = 0; k < 27; ++k) g[k] = nrow[k];
        g[27] = 0;
    }

    f32x4 acc[4] = {};

#pragma unroll
    for (int kg = 0; kg < 28; kg += 7) {
        // phase 1: issue all 14 gather loads for this group (stay in flight)
        bf16x8 a0[7], a1[7];
#pragma unroll
        for (int j = 0; j < 7; ++j) {
            int k = kg + j;
            a0[j] = (bf16x8)0; a1[j] = (bf16x8)0;
            if ((mbits >> k) & 1u) {
                const unsigned short* src = xb + ((long)(unsigned)g[k] << 6) + (lh << 3);
                a0[j] = *(const bf16x8*)src;          // ci 8*lh..
                a1[j] = *(const bf16x8*)(src + 32);   // ci 32+8*lh..
            }
        }
        // phase 2: B loads (L1-hot) + MFMAs; waits resolve per-fragment
#pragma unroll
        for (int j = 0; j < 7; ++j) {
            int k = kg + j;
            if (k < K) {
                const unsigned short* wk = Wt + ((long)k << 12) + lr * 64 + (lh << 3);
#pragma unroll
                for (int cb = 0; cb < 4; ++cb) {
                    bf16x8 b0 = *(const bf16x8*)(wk + cb * 1024);
                    bf16x8 b1 = *(const bf16x8*)(wk + cb * 1024 + 32);
                    acc[cb] = __builtin_amdgcn_mfma_f32_16x16x32_bf16(a0[j], b0, acc[cb], 0, 0, 0);
                    acc[cb] = __builtin_amdgcn_mfma_f32_16x16x32_bf16(a1[j], b1, acc[cb], 0, 0, 0);
                }
            }
        }
    }

    // ---- epilogue: D row = 4*lh + r (within wave tile), col = cb*16 + lr ----
#pragma unroll
    for (int cb = 0; cb < 4; ++cb) {
        int col = cb * 16 + lr;
        float bv = bias[col];
#pragma unroll
        for (int r = 0; r < 4; ++r) {
            int orow = base + w * 16 + lh * 4 + r;
            if (orow < N) {
                long o = (long)orow * 64 + col;
                float v = acc[cb][r] + bv;
                if (MODE == 0) {
                    v = fmaxf(v, 0.f);
                    ((unsigned short*)outp)[o] = f2bf(v);
                } else {
                    ((float*)outp)[o] = v + resid[o];
                }
            }
        }
    }
}

static inline size_t align256(size_t x) { return (x + 255) & ~(size_t)255; }

extern "C" void kernel_launch(void* const* d_in, const int* in_sizes, int n_in,
                              void* d_out, int out_size, void* d_ws, size_t ws_size,
                              hipStream_t stream) {
    const float* x    = (const float*)d_in[0];
    const int*   nbr  = (const int*)d_in[1];
    const void*  mask = d_in[2];
    const float* W0   = (const float*)d_in[3];
    const float* b0   = (const float*)d_in[4];
    const float* W1   = (const float*)d_in[5];
    const float* b1   = (const float*)d_in[6];

    const int NC = in_sizes[0];      // N*64
    const int N  = NC / 64;
    const int K  = in_sizes[1] / N;  // 27
    const int KP = 28;               // padded K for the unrolled kernel

    char* ws = (char*)d_ws;
    size_t xb_bytes = (size_t)NC * 2;
    size_t wt_bytes = (size_t)KP * 64 * 64 * 2;
    size_t xb_off   = 0;
    size_t hb_off   = xb_off + align256(xb_bytes);
    size_t wt0_off  = hb_off + align256(xb_bytes);
    size_t wt1_off  = wt0_off + align256(wt_bytes);
    size_t flag_off = wt1_off + align256(wt_bytes);

    unsigned short* xb  = (unsigned short*)(ws + xb_off);
    unsigned short* hb  = (unsigned short*)(ws + hb_off);
    unsigned short* wt0 = (unsigned short*)(ws + wt0_off);
    unsigned short* wt1 = (unsigned short*)(ws + wt1_off);
    int* flag           = (int*)(ws + flag_off);

    int n4 = NC / 4;
    prep_x<<<(n4 + 255) / 256, 256, 0, stream>>>((const f32x4*)x, (u16x4*)xb, n4);
    prep_w<<<KP, 256, 0, stream>>>(W0, wt0, K);
    prep_w<<<KP, 256, 0, stream>>>(W1, wt1, K);
    detect_mask<<<1, 1024, 0, stream>>>((const unsigned int*)mask, flag);

    int nblocks = (N + 63) / 64;
    conv_mfma<0><<<nblocks, 256, 0, stream>>>(xb, nbr, mask, flag, wt0, b0, nullptr, hb, N, K);
    conv_mfma<1><<<nblocks, 256, 0, stream>>>(hb, nbr, mask, flag, wt1, b1, x, d_out, N, K);
}